// Round 1
// baseline (164.010 us; speedup 1.0000x reference)
//
#include <hip/hip_runtime.h>
#include <math.h>

// Problem constants (B=4, S=2048, D=2048, E=64, K=2)
#define NTOK   8192      // B*S
#define DDIM   2048
#define NEXP   64
#define TOPK   2
#define TPB    8         // tokens per block
#define NWAVE  4         // waves per block, split K
#define KSLICE (DDIM / NWAVE)   // 512

#define GATED_SZ (NTOK * NEXP)          // 524288
#define IDX_OFF  GATED_SZ               // 524288
#define VALS_OFF (GATED_SZ + NTOK * 2)  // 540672

__global__ __launch_bounds__(256, 4) void moe_gate_kernel(
    const float* __restrict__ x,
    const float* __restrict__ W,
    const float* __restrict__ noise_w,
    const float* __restrict__ noise,
    float* __restrict__ out)
{
    // partial dot products: [token][wave][expert]
    __shared__ float part[TPB * NWAVE * NEXP];   // 8 KB

    const int lane = threadIdx.x & 63;
    const int wv   = __builtin_amdgcn_readfirstlane((int)(threadIdx.x >> 6));
    const int e    = lane;                 // lane == expert
    const int tokBase = blockIdx.x * TPB;
    const int kOff = wv * KSLICE;

    float acc[TPB];
#pragma unroll
    for (int t = 0; t < TPB; ++t) acc[t] = 0.f;

    // W row for this expert, K-slice for this wave
    const float4* Wrow = (const float4*)(W + (size_t)e * DDIM + kOff);
    const float*  xbase = x + (size_t)tokBase * DDIM + kOff;

#pragma unroll 2
    for (int q = 0; q < KSLICE / 4; ++q) {
        const float4 wq = Wrow[q];
#pragma unroll
        for (int t = 0; t < TPB; ++t) {
            // wave-uniform address -> scalar/broadcast load
            const float4 xq = *(const float4*)(xbase + (size_t)t * DDIM + q * 4);
            acc[t] = fmaf(wq.x, xq.x, acc[t]);
            acc[t] = fmaf(wq.y, xq.y, acc[t]);
            acc[t] = fmaf(wq.z, xq.z, acc[t]);
            acc[t] = fmaf(wq.w, xq.w, acc[t]);
        }
    }

#pragma unroll
    for (int t = 0; t < TPB; ++t)
        part[(t * NWAVE + wv) * NEXP + e] = acc[t];
    __syncthreads();

    // Epilogue: wave wv handles tokens 2*wv and 2*wv+1
#pragma unroll
    for (int i = 0; i < 2; ++i) {
        const int t   = wv * 2 + i;
        const int tok = tokBase + t;

        float v = part[(t * NWAVE + 0) * NEXP + e]
                + part[(t * NWAVE + 1) * NEXP + e]
                + part[(t * NWAVE + 2) * NEXP + e]
                + part[(t * NWAVE + 3) * NEXP + e];

        // noise injection (fp32, matches reference order)
        v += noise[(size_t)tok * NEXP + e] * noise_w[e];

        // top-1: butterfly max with lax.top_k tie-break (lower index wins)
        float m1 = v; int i1 = e;
#pragma unroll
        for (int s = 32; s > 0; s >>= 1) {
            float ov = __shfl_xor(m1, s, 64);
            int   oi = __shfl_xor(i1, s, 64);
            if (ov > m1 || (ov == m1 && oi < i1)) { m1 = ov; i1 = oi; }
        }
        // top-2: mask winner, reduce again
        float vm = (e == i1) ? -INFINITY : v;
        float m2 = vm; int i2 = e;
#pragma unroll
        for (int s = 32; s > 0; s >>= 1) {
            float ov = __shfl_xor(m2, s, 64);
            int   oi = __shfl_xor(i2, s, 64);
            if (ov > m2 || (ov == m2 && oi < i2)) { m2 = ov; i2 = oi; }
        }

        // softmax over (m1, m2); m1 >= m2 so max = m1
        const float e2 = expf(m2 - m1);
        const float inv = 1.f / (1.f + e2);
        const float p1 = inv;
        const float p2 = e2 * inv;

        // gated: zeros everywhere except top-2 slots (must write zeros: d_out poisoned)
        float g = 0.f;
        if (e == i1) g = p1;
        else if (e == i2) g = p2;
        out[(size_t)tok * NEXP + e] = g;

        if (lane == 0) {
            out[IDX_OFF  + tok * 2 + 0] = (float)i1;
            out[IDX_OFF  + tok * 2 + 1] = (float)i2;
            out[VALS_OFF + tok * 2 + 0] = m1;
            out[VALS_OFF + tok * 2 + 1] = m2;
        }
    }
}

extern "C" void kernel_launch(void* const* d_in, const int* in_sizes, int n_in,
                              void* d_out, int out_size, void* d_ws, size_t ws_size,
                              hipStream_t stream) {
    const float* x      = (const float*)d_in[0];
    const float* W      = (const float*)d_in[1];
    const float* nw     = (const float*)d_in[2];
    const float* noise  = (const float*)d_in[3];
    // d_in[4] is k==2, hardcoded
    float* out = (float*)d_out;

    dim3 grid(NTOK / TPB);   // 1024 blocks
    dim3 block(256);
    hipLaunchKernelGGL(moe_gate_kernel, grid, block, 0, stream,
                       x, W, nw, noise, out);
}